// Round 1
// baseline (1086.293 us; speedup 1.0000x reference)
//
#include <hip/hip_runtime.h>
#include <math.h>

typedef short bf16x8 __attribute__((ext_vector_type(8)));
typedef float f32x4 __attribute__((ext_vector_type(4)));

__device__ __forceinline__ short f2bf(float f) {
    union { float f; unsigned u; } v; v.f = f;
    unsigned r = v.u + 0x7fffu + ((v.u >> 16) & 1u);
    return (short)(r >> 16);
}

// shifted softplus: 2*log(1+exp(0.5x)), numerically-stable form
__device__ __forceinline__ float ssp(float x) {
    float h = 0.5f * x;
    return 2.0f * (fmaxf(h, 0.0f) + __logf(1.0f + __expf(-fabsf(h))));
}

// ---------------------------------------------------------------------------
// CSR-build kernels: histogram -> hierarchical exclusive scan -> perm scatter
// All int atomics land in a 400 KB L2-hot region (3.2M total vs 102M float
// atomics in the old path).
// ---------------------------------------------------------------------------
__global__ void hist_kernel(const int* __restrict__ dst, int* __restrict__ counts,
                            int n_edges) {
    int i = blockIdx.x * blockDim.x + threadIdx.x;
    int gs = gridDim.x * blockDim.x;
    for (int e = i; e < n_edges; e += gs) atomicAdd(&counts[dst[e]], 1);
}

__global__ __launch_bounds__(256) void scan_blocks(const int* __restrict__ counts,
        int* __restrict__ base, int* __restrict__ partials, int n) {
    __shared__ int wsum[4];
    const int tid = threadIdx.x, lane = tid & 63, wv = tid >> 6;
    const int i0 = blockIdx.x * 1024 + tid * 4;
    int c[4], ts = 0;
    #pragma unroll
    for (int j = 0; j < 4; ++j) { c[j] = (i0 + j < n) ? counts[i0 + j] : 0; ts += c[j]; }
    int x = ts;
    #pragma unroll
    for (int off = 1; off < 64; off <<= 1) {
        int y = __shfl_up(x, off);
        if (lane >= off) x += y;
    }
    if (lane == 63) wsum[wv] = x;
    __syncthreads();
    int woff = 0;
    for (int w = 0; w < wv; ++w) woff += wsum[w];
    int run = woff + x - ts;               // exclusive offset for this thread
    #pragma unroll
    for (int j = 0; j < 4; ++j) { if (i0 + j < n) base[i0 + j] = run; run += c[j]; }
    if (tid == 255) partials[blockIdx.x] = woff + x;   // block total
}

__global__ void scan_partials(int* __restrict__ partials, int nblk) {
    const int lane = threadIdx.x;          // launched with 64 threads (1 wave)
    int carry = 0;
    for (int b = 0; b < nblk; b += 64) {
        const int i = b + lane;
        int v = (i < nblk) ? partials[i] : 0;
        int x = v;
        #pragma unroll
        for (int off = 1; off < 64; off <<= 1) {
            int y = __shfl_up(x, off);
            if (lane >= off) x += y;
        }
        if (i < nblk) partials[i] = carry + x - v;     // exclusive
        carry += __shfl(x, 63);
    }
}

__global__ __launch_bounds__(256) void add_offsets(int* __restrict__ base,
        const int* __restrict__ partials, int n, int total) {
    const int i0 = blockIdx.x * 1024 + threadIdx.x * 4;
    const int p = partials[blockIdx.x];
    #pragma unroll
    for (int j = 0; j < 4; ++j) if (i0 + j < n) base[i0 + j] += p;
    if (blockIdx.x == 0 && threadIdx.x == 0) base[n] = total;
}

__global__ void scatter_kernel(const int* __restrict__ dst, const int* __restrict__ base,
        int* __restrict__ cursor, int* __restrict__ perm, int n_edges) {
    int i = blockIdx.x * blockDim.x + threadIdx.x;
    int gs = gridDim.x * blockDim.x;
    for (int e = i; e < n_edges; e += gs) {
        int d = dst[e];
        int off = atomicAdd(&cursor[d], 1);
        perm[base[d] + off] = e;
    }
}

// ---------------------------------------------------------------------------
// Main kernel: one wave per destination node. Walks the node's edge list in
// 16-row MFMA tiles (same verified MLP path as before), accumulates
// (e2+b2)*nw[src] in registers, cross-quad shfl reduce, ONE coalesced plain
// store per node. Zero float atomics.
// ---------------------------------------------------------------------------
__global__ __launch_bounds__(256, 2) void cfconv_gather(
    const float* __restrict__ nw, const float* __restrict__ rbf,
    const float* __restrict__ W1, const float* __restrict__ b1,
    const float* __restrict__ W2, const float* __restrict__ b2,
    const int* __restrict__ src,
    const int* __restrict__ perm, const int* __restrict__ base,
    float* __restrict__ out, int n_nodes)
{
    // per-wave H tile for C-layout -> A-layout transform; stride 72 keeps
    // ds_read_b128 16B-aligned (144B rows), 2-way conflicts only (free)
    __shared__ __align__(16) short lds_h[4][16 * 72];

    const int tid  = threadIdx.x;
    const int wave = tid >> 6;
    const int lane = tid & 63;
    const int l16  = lane & 15;
    const int quad = lane >> 4;

    // W1/W2 in B-operand fragment layout, resident for the whole kernel.
    bf16x8 w1f[2][4], w2f[2][4];
    #pragma unroll
    for (int ks = 0; ks < 2; ++ks) {
        #pragma unroll
        for (int nt = 0; nt < 4; ++nt) {
            const int col = l16 + 16 * nt;
            const int k0  = quad * 8 + 32 * ks;
            bf16x8 a, b;
            #pragma unroll
            for (int j = 0; j < 8; ++j) {
                a[j] = f2bf(W1[(k0 + j) * 64 + col]);
                b[j] = f2bf(W2[(k0 + j) * 64 + col]);
            }
            w1f[ks][nt] = a;
            w2f[ks][nt] = b;
        }
    }
    float b1v[4], b2v[4];
    #pragma unroll
    for (int nt = 0; nt < 4; ++nt) {
        b1v[nt] = b1[l16 + 16 * nt];
        b2v[nt] = b2[l16 + 16 * nt];
    }

    short* myh = lds_h[wave];
    const int gw = blockIdx.x * 4 + wave;
    const int stride = gridDim.x * 4;

    for (int n = gw; n < n_nodes; n += stride) {
        const int s0 = base[n], s1 = base[n + 1];
        float hsum[4] = {0.f, 0.f, 0.f, 0.f};

        for (int p = s0; p < s1; p += 16) {
            const int v = s1 - p;   // >= 1; lanes compare against <=15 so no min needed

            // A fragment rows: edge for row m = l16 (invalid rows clamp to a
            // valid edge; their contribution is masked out in the epilogue)
            const int e_a = perm[(l16 < v) ? (p + l16) : p];
            const float* rp = rbf + (size_t)e_a * 64 + quad * 8;
            bf16x8 af[2];
            #pragma unroll
            for (int ks = 0; ks < 2; ++ks) {
                float4 lo = *(const float4*)(rp + 32 * ks);
                float4 hi = *(const float4*)(rp + 32 * ks + 4);
                bf16x8 a;
                a[0] = f2bf(lo.x); a[1] = f2bf(lo.y); a[2] = f2bf(lo.z); a[3] = f2bf(lo.w);
                a[4] = f2bf(hi.x); a[5] = f2bf(hi.y); a[6] = f2bf(hi.z); a[7] = f2bf(hi.w);
                af[ks] = a;
            }

            // GEMM1: H = rbf @ W1
            f32x4 acc[4] = { {0.f,0.f,0.f,0.f}, {0.f,0.f,0.f,0.f},
                             {0.f,0.f,0.f,0.f}, {0.f,0.f,0.f,0.f} };
            #pragma unroll
            for (int nt = 0; nt < 4; ++nt)
                #pragma unroll
                for (int ks = 0; ks < 2; ++ks)
                    acc[nt] = __builtin_amdgcn_mfma_f32_16x16x32_bf16(
                        af[ks], w1f[ks][nt], acc[nt], 0, 0, 0);

            // bias + ssp, LDS transpose C-layout -> A-layout
            #pragma unroll
            for (int nt = 0; nt < 4; ++nt)
                #pragma unroll
                for (int r = 0; r < 4; ++r)
                    myh[(quad * 4 + r) * 72 + l16 + 16 * nt] =
                        f2bf(ssp(acc[nt][r] + b1v[nt]));

            // same-wave readback (compiler inserts lgkmcnt wait)
            bf16x8 hf[2];
            #pragma unroll
            for (int ks = 0; ks < 2; ++ks)
                hf[ks] = *(const bf16x8*)(myh + l16 * 72 + quad * 8 + 32 * ks);

            // GEMM2: E2 = H @ W2
            f32x4 acc2[4] = { {0.f,0.f,0.f,0.f}, {0.f,0.f,0.f,0.f},
                              {0.f,0.f,0.f,0.f}, {0.f,0.f,0.f,0.f} };
            #pragma unroll
            for (int nt = 0; nt < 4; ++nt)
                #pragma unroll
                for (int ks = 0; ks < 2; ++ks)
                    acc2[nt] = __builtin_amdgcn_mfma_f32_16x16x32_bf16(
                        hf[ks], w2f[ks][nt], acc2[nt], 0, 0, 0);

            // accumulate m = nw[src]*(e2+b2) into per-lane column sums
            #pragma unroll
            for (int r = 0; r < 4; ++r) {
                const int q = quad * 4 + r;   // edge slot in tile
                if (q < v) {
                    const int e = perm[p + q];
                    const int s = src[e];
                    const float* nwp = nw + (size_t)s * 64;
                    #pragma unroll
                    for (int nt = 0; nt < 4; ++nt)
                        hsum[nt] += (acc2[nt][r] + b2v[nt]) * nwp[l16 + 16 * nt];
                }
            }
        }

        // reduce across quads: after this, every quad holds the full sum
        #pragma unroll
        for (int nt = 0; nt < 4; ++nt) {
            float x = hsum[nt];
            x += __shfl_xor(x, 16);
            x += __shfl_xor(x, 32);
            hsum[nt] = x;
        }
        // quad q stores column block q -> one fully-coalesced 256B store/wave
        float o = hsum[0];
        o = (quad == 1) ? hsum[1] : o;
        o = (quad == 2) ? hsum[2] : o;
        o = (quad == 3) ? hsum[3] : o;
        out[(size_t)n * 64 + quad * 16 + l16] = o;
    }
}

// ---------------------------------------------------------------------------
// Fallback: original atomic-scatter kernel (used only if workspace too small)
// ---------------------------------------------------------------------------
__global__ __launch_bounds__(256, 2) void cfconv_kernel(
    const float* __restrict__ nw, const float* __restrict__ rbf,
    const float* __restrict__ W1, const float* __restrict__ b1,
    const float* __restrict__ W2, const float* __restrict__ b2,
    const int* __restrict__ src, const int* __restrict__ dst,
    float* __restrict__ out, int n_edges)
{
    __shared__ __align__(16) short lds_h[4][16 * 72];

    const int tid  = threadIdx.x;
    const int wave = tid >> 6;
    const int lane = tid & 63;
    const int l16  = lane & 15;
    const int quad = lane >> 4;

    bf16x8 w1f[2][4], w2f[2][4];
    #pragma unroll
    for (int ks = 0; ks < 2; ++ks) {
        #pragma unroll
        for (int nt = 0; nt < 4; ++nt) {
            const int col = l16 + 16 * nt;
            const int k0  = quad * 8 + 32 * ks;
            bf16x8 a, b;
            #pragma unroll
            for (int j = 0; j < 8; ++j) {
                a[j] = f2bf(W1[(k0 + j) * 64 + col]);
                b[j] = f2bf(W2[(k0 + j) * 64 + col]);
            }
            w1f[ks][nt] = a;
            w2f[ks][nt] = b;
        }
    }
    float b1v[4], b2v[4];
    #pragma unroll
    for (int nt = 0; nt < 4; ++nt) {
        b1v[nt] = b1[l16 + 16 * nt];
        b2v[nt] = b2[l16 + 16 * nt];
    }

    short* myh = lds_h[wave];
    const int ntiles = (n_edges + 15) >> 4;
    const int gw = blockIdx.x * 4 + wave;
    const int stride = gridDim.x * 4;

    for (int t = gw; t < ntiles; t += stride) {
        const int e0 = t * 16;
        int arow = e0 + l16;
        if (arow >= n_edges) arow = n_edges - 1;
        const float* rp = rbf + (size_t)arow * 64 + quad * 8;
        bf16x8 af[2];
        #pragma unroll
        for (int ks = 0; ks < 2; ++ks) {
            float4 lo = *(const float4*)(rp + 32 * ks);
            float4 hi = *(const float4*)(rp + 32 * ks + 4);
            bf16x8 a;
            a[0] = f2bf(lo.x); a[1] = f2bf(lo.y); a[2] = f2bf(lo.z); a[3] = f2bf(lo.w);
            a[4] = f2bf(hi.x); a[5] = f2bf(hi.y); a[6] = f2bf(hi.z); a[7] = f2bf(hi.w);
            af[ks] = a;
        }

        f32x4 acc[4] = { {0.f,0.f,0.f,0.f}, {0.f,0.f,0.f,0.f},
                         {0.f,0.f,0.f,0.f}, {0.f,0.f,0.f,0.f} };
        #pragma unroll
        for (int nt = 0; nt < 4; ++nt)
            #pragma unroll
            for (int ks = 0; ks < 2; ++ks)
                acc[nt] = __builtin_amdgcn_mfma_f32_16x16x32_bf16(
                    af[ks], w1f[ks][nt], acc[nt], 0, 0, 0);

        #pragma unroll
        for (int nt = 0; nt < 4; ++nt)
            #pragma unroll
            for (int r = 0; r < 4; ++r)
                myh[(quad * 4 + r) * 72 + l16 + 16 * nt] =
                    f2bf(ssp(acc[nt][r] + b1v[nt]));

        bf16x8 hf[2];
        #pragma unroll
        for (int ks = 0; ks < 2; ++ks)
            hf[ks] = *(const bf16x8*)(myh + l16 * 72 + quad * 8 + 32 * ks);

        f32x4 acc2[4] = { {0.f,0.f,0.f,0.f}, {0.f,0.f,0.f,0.f},
                          {0.f,0.f,0.f,0.f}, {0.f,0.f,0.f,0.f} };
        #pragma unroll
        for (int nt = 0; nt < 4; ++nt)
            #pragma unroll
            for (int ks = 0; ks < 2; ++ks)
                acc2[nt] = __builtin_amdgcn_mfma_f32_16x16x32_bf16(
                    hf[ks], w2f[ks][nt], acc2[nt], 0, 0, 0);

        #pragma unroll
        for (int r = 0; r < 4; ++r) {
            const int e = e0 + quad * 4 + r;
            if (e < n_edges) {
                const int s = src[e], d = dst[e];
                const float* nwp = nw + (size_t)s * 64;
                float* op = out + (size_t)d * 64;
                #pragma unroll
                for (int nt = 0; nt < 4; ++nt) {
                    const int col = l16 + 16 * nt;
                    atomicAdd(op + col, (acc2[nt][r] + b2v[nt]) * nwp[col]);
                }
            }
        }
    }
}

extern "C" void kernel_launch(void* const* d_in, const int* in_sizes, int n_in,
                              void* d_out, int out_size, void* d_ws, size_t ws_size,
                              hipStream_t stream) {
    const float* nw  = (const float*)d_in[0];
    const float* rbf = (const float*)d_in[1];
    const float* W1  = (const float*)d_in[2];
    const float* b1  = (const float*)d_in[3];
    const float* W2  = (const float*)d_in[4];
    const float* b2  = (const float*)d_in[5];
    const int*   src = (const int*)d_in[6];
    const int*   dst = (const int*)d_in[7];
    float* out = (float*)d_out;
    const int n_edges = in_sizes[6];
    const int n_nodes = out_size / 64;

    // workspace layout: base[n_nodes+1] | counts[n_nodes] | partials[1024] | perm[n_edges]
    const size_t need = ((size_t)(n_nodes + 1) + (size_t)n_nodes + 1024 + (size_t)n_edges)
                        * sizeof(int);

    if (ws_size >= need) {
        int* base     = (int*)d_ws;
        int* counts   = base + (n_nodes + 1);
        int* partials = counts + n_nodes;
        int* perm     = partials + 1024;

        const int nblk = (n_nodes + 1023) / 1024;
        int eblocks = (n_edges + 255) / 256;
        if (eblocks > 8192) eblocks = 8192;

        hipMemsetAsync(counts, 0, (size_t)n_nodes * sizeof(int), stream);
        hipLaunchKernelGGL(hist_kernel, dim3(eblocks), dim3(256), 0, stream,
                           dst, counts, n_edges);
        hipLaunchKernelGGL(scan_blocks, dim3(nblk), dim3(256), 0, stream,
                           counts, base, partials, n_nodes);
        hipLaunchKernelGGL(scan_partials, dim3(1), dim3(64), 0, stream,
                           partials, nblk);
        hipLaunchKernelGGL(add_offsets, dim3(nblk), dim3(256), 0, stream,
                           base, partials, n_nodes, n_edges);
        hipMemsetAsync(counts, 0, (size_t)n_nodes * sizeof(int), stream);
        hipLaunchKernelGGL(scatter_kernel, dim3(eblocks), dim3(256), 0, stream,
                           dst, base, counts, perm, n_edges);

        const int nodeblocks = (n_nodes + 3) / 4;   // one wave per node
        hipLaunchKernelGGL(cfconv_gather, dim3(nodeblocks), dim3(256), 0, stream,
                           nw, rbf, W1, b1, W2, b2, src, perm, base, out, n_nodes);
    } else {
        // fallback: original atomic path
        hipMemsetAsync(out, 0, (size_t)out_size * sizeof(float), stream);
        hipLaunchKernelGGL(cfconv_kernel, dim3(1024), dim3(256), 0, stream,
                           nw, rbf, W1, b1, W2, b2, src, dst, out, n_edges);
    }
}

// Round 2
// 883.758 us; speedup vs baseline: 1.2292x; 1.2292x over previous
//
#include <hip/hip_runtime.h>
#include <math.h>

typedef short bf16x8 __attribute__((ext_vector_type(8)));
typedef float f32x4 __attribute__((ext_vector_type(4)));

__device__ __forceinline__ short f2bf(float f) {
    union { float f; unsigned u; } v; v.f = f;
    unsigned r = v.u + 0x7fffu + ((v.u >> 16) & 1u);
    return (short)(r >> 16);
}

// shifted softplus: 2*log(1+exp(0.5x)), numerically-stable form
__device__ __forceinline__ float ssp(float x) {
    float h = 0.5f * x;
    return 2.0f * (fmaxf(h, 0.0f) + __logf(1.0f + __expf(-fabsf(h))));
}

// ---------------------------------------------------------------------------
// CSR-build kernels: histogram -> hierarchical exclusive scan -> perm scatter.
// All int atomics land in a 400 KB L2-hot region.
// ---------------------------------------------------------------------------
__global__ void hist_kernel(const int* __restrict__ dst, int* __restrict__ counts,
                            int n_edges) {
    int i = blockIdx.x * blockDim.x + threadIdx.x;
    int gs = gridDim.x * blockDim.x;
    for (int e = i; e < n_edges; e += gs) atomicAdd(&counts[dst[e]], 1);
}

__global__ __launch_bounds__(256) void scan_blocks(const int* __restrict__ counts,
        int* __restrict__ base, int* __restrict__ partials, int n) {
    __shared__ int wsum[4];
    const int tid = threadIdx.x, lane = tid & 63, wv = tid >> 6;
    const int i0 = blockIdx.x * 1024 + tid * 4;
    int c[4], ts = 0;
    #pragma unroll
    for (int j = 0; j < 4; ++j) { c[j] = (i0 + j < n) ? counts[i0 + j] : 0; ts += c[j]; }
    int x = ts;
    #pragma unroll
    for (int off = 1; off < 64; off <<= 1) {
        int y = __shfl_up(x, off);
        if (lane >= off) x += y;
    }
    if (lane == 63) wsum[wv] = x;
    __syncthreads();
    int woff = 0;
    for (int w = 0; w < wv; ++w) woff += wsum[w];
    int run = woff + x - ts;               // exclusive offset for this thread
    #pragma unroll
    for (int j = 0; j < 4; ++j) { if (i0 + j < n) base[i0 + j] = run; run += c[j]; }
    if (tid == 255) partials[blockIdx.x] = woff + x;   // block total
}

__global__ void scan_partials(int* __restrict__ partials, int nblk) {
    const int lane = threadIdx.x;          // launched with 64 threads (1 wave)
    int carry = 0;
    for (int b = 0; b < nblk; b += 64) {
        const int i = b + lane;
        int v = (i < nblk) ? partials[i] : 0;
        int x = v;
        #pragma unroll
        for (int off = 1; off < 64; off <<= 1) {
            int y = __shfl_up(x, off);
            if (lane >= off) x += y;
        }
        if (i < nblk) partials[i] = carry + x - v;     // exclusive
        carry += __shfl(x, 63);
    }
}

__global__ __launch_bounds__(256) void add_offsets(int* __restrict__ base,
        const int* __restrict__ partials, int n, int total) {
    const int i0 = blockIdx.x * 1024 + threadIdx.x * 4;
    const int p = partials[blockIdx.x];
    #pragma unroll
    for (int j = 0; j < 4; ++j) if (i0 + j < n) base[i0 + j] += p;
    if (blockIdx.x == 0 && threadIdx.x == 0) base[n] = total;
}

// scatter edges into dst-sorted order; also materialize src/dst in perm order
// so the hot kernel reads them fully coalesced (no random 4B gathers).
__global__ void scatter_kernel(const int* __restrict__ dst, const int* __restrict__ src,
        const int* __restrict__ base, int* __restrict__ cursor,
        int* __restrict__ perm, int* __restrict__ sp, int* __restrict__ dp,
        int n_edges) {
    int i = blockIdx.x * blockDim.x + threadIdx.x;
    int gs = gridDim.x * blockDim.x;
    for (int e = i; e < n_edges; e += gs) {
        int d = dst[e];
        int off = atomicAdd(&cursor[d], 1);
        int pos = base[d] + off;
        perm[pos] = e;
        sp[pos] = src[e];
        dp[pos] = d;
    }
}

// ---------------------------------------------------------------------------
// Main kernel: waves grid-stride over contiguous 16-edge tiles of the
// PERMUTED (dst-sorted) edge list. Same verified MFMA/ssp/LDS-transpose MLP.
// Epilogue: in-register segmented reduction over the ~1-3 distinct dst nodes
// in the tile, one 64-lane atomicAdd per distinct dst (~51 MB atomic traffic
// vs 400 MB in the unsorted kernel). Uniform work per wave -> no imbalance.
// ---------------------------------------------------------------------------
__global__ __launch_bounds__(256, 2) void cfconv_perm(
    const float* __restrict__ nw, const float* __restrict__ rbf,
    const float* __restrict__ W1, const float* __restrict__ b1,
    const float* __restrict__ W2, const float* __restrict__ b2,
    const int* __restrict__ perm, const int* __restrict__ sp,
    const int* __restrict__ dp,
    float* __restrict__ out, int n_edges)
{
    // per-wave H tile for C-layout -> A-layout transform; stride 72 keeps
    // ds_read_b128 16B-aligned (144B rows), 2-way conflicts only (free)
    __shared__ __align__(16) short lds_h[4][16 * 72];

    const int tid  = threadIdx.x;
    const int wave = tid >> 6;
    const int lane = tid & 63;
    const int l16  = lane & 15;
    const int quad = lane >> 4;

    // W1/W2 in B-operand fragment layout, resident for the whole kernel.
    bf16x8 w1f[2][4], w2f[2][4];
    #pragma unroll
    for (int ks = 0; ks < 2; ++ks) {
        #pragma unroll
        for (int nt = 0; nt < 4; ++nt) {
            const int col = l16 + 16 * nt;
            const int k0  = quad * 8 + 32 * ks;
            bf16x8 a, b;
            #pragma unroll
            for (int j = 0; j < 8; ++j) {
                a[j] = f2bf(W1[(k0 + j) * 64 + col]);
                b[j] = f2bf(W2[(k0 + j) * 64 + col]);
            }
            w1f[ks][nt] = a;
            w2f[ks][nt] = b;
        }
    }
    float b1v[4], b2v[4];
    #pragma unroll
    for (int nt = 0; nt < 4; ++nt) {
        b1v[nt] = b1[l16 + 16 * nt];
        b2v[nt] = b2[l16 + 16 * nt];
    }

    short* myh = lds_h[wave];
    const int ntiles = (n_edges + 15) >> 4;
    const int gw = blockIdx.x * 4 + wave;
    const int stride = gridDim.x * 4;

    for (int t = gw; t < ntiles; t += stride) {
        const int p0 = t * 16;

        // A fragment rows: rbf row of edge perm[p0 + l16] (256B gather,
        // every byte of the segment consumed -> near-streaming efficiency)
        int prow = p0 + l16;
        if (prow >= n_edges) prow = n_edges - 1;   // safe clamp
        const int e_a = perm[prow];
        const float* rp = rbf + (size_t)e_a * 64 + quad * 8;
        bf16x8 af[2];
        #pragma unroll
        for (int ks = 0; ks < 2; ++ks) {
            float4 lo = *(const float4*)(rp + 32 * ks);
            float4 hi = *(const float4*)(rp + 32 * ks + 4);
            bf16x8 a;
            a[0] = f2bf(lo.x); a[1] = f2bf(lo.y); a[2] = f2bf(lo.z); a[3] = f2bf(lo.w);
            a[4] = f2bf(hi.x); a[5] = f2bf(hi.y); a[6] = f2bf(hi.z); a[7] = f2bf(hi.w);
            af[ks] = a;
        }

        // GEMM1: H = rbf @ W1
        f32x4 acc[4] = { {0.f,0.f,0.f,0.f}, {0.f,0.f,0.f,0.f},
                         {0.f,0.f,0.f,0.f}, {0.f,0.f,0.f,0.f} };
        #pragma unroll
        for (int nt = 0; nt < 4; ++nt)
            #pragma unroll
            for (int ks = 0; ks < 2; ++ks)
                acc[nt] = __builtin_amdgcn_mfma_f32_16x16x32_bf16(
                    af[ks], w1f[ks][nt], acc[nt], 0, 0, 0);

        // bias + ssp, LDS transpose C-layout -> A-layout
        #pragma unroll
        for (int nt = 0; nt < 4; ++nt)
            #pragma unroll
            for (int r = 0; r < 4; ++r)
                myh[(quad * 4 + r) * 72 + l16 + 16 * nt] =
                    f2bf(ssp(acc[nt][r] + b1v[nt]));

        // same-wave readback (compiler inserts lgkmcnt wait)
        bf16x8 hf[2];
        #pragma unroll
        for (int ks = 0; ks < 2; ++ks)
            hf[ks] = *(const bf16x8*)(myh + l16 * 72 + quad * 8 + 32 * ks);

        // GEMM2: E2 = H @ W2
        f32x4 acc2[4] = { {0.f,0.f,0.f,0.f}, {0.f,0.f,0.f,0.f},
                          {0.f,0.f,0.f,0.f}, {0.f,0.f,0.f,0.f} };
        #pragma unroll
        for (int nt = 0; nt < 4; ++nt)
            #pragma unroll
            for (int ks = 0; ks < 2; ++ks)
                acc2[nt] = __builtin_amdgcn_mfma_f32_16x16x32_bf16(
                    hf[ks], w2f[ks][nt], acc2[nt], 0, 0, 0);

        // per-row messages m = nw[src]*(e2+b2); this lane owns rows quad*4+r,
        // columns l16+16nt. sp/dp reads are coalesced (perm-ordered arrays).
        int   dr[4];
        float msg[4][4];
        #pragma unroll
        for (int r = 0; r < 4; ++r) {
            const int row = p0 + quad * 4 + r;
            if (row < n_edges) {
                const int s = sp[row];
                dr[r] = dp[row];
                const float* nwp = nw + (size_t)s * 64;
                #pragma unroll
                for (int nt = 0; nt < 4; ++nt)
                    msg[r][nt] = (acc2[nt][r] + b2v[nt]) * nwp[l16 + 16 * nt];
            } else {
                dr[r] = 0x7fffffff;     // sentinel: never matched, never min
                #pragma unroll
                for (int nt = 0; nt < 4; ++nt) msg[r][nt] = 0.f;
            }
        }

        // segmented reduction over the (sorted) dst values in this tile.
        // Typically 1-3 iterations; all lanes agree on cur.
        int cur = __shfl(dr[0], l16);   // dst of row 0 (held by quad-0 lanes)
        while (true) {
            float s0 = 0.f, s1 = 0.f, s2 = 0.f, s3 = 0.f;
            #pragma unroll
            for (int r = 0; r < 4; ++r) {
                if (dr[r] == cur) {
                    s0 += msg[r][0]; s1 += msg[r][1];
                    s2 += msg[r][2]; s3 += msg[r][3];
                }
            }
            // cross-quad reduce (same columns, different rows)
            s0 += __shfl_xor(s0, 16); s0 += __shfl_xor(s0, 32);
            s1 += __shfl_xor(s1, 16); s1 += __shfl_xor(s1, 32);
            s2 += __shfl_xor(s2, 16); s2 += __shfl_xor(s2, 32);
            s3 += __shfl_xor(s3, 16); s3 += __shfl_xor(s3, 32);
            // quad q contributes column block q -> 64 contiguous atomics/wave
            float o = s0;
            o = (quad == 1) ? s1 : o;
            o = (quad == 2) ? s2 : o;
            o = (quad == 3) ? s3 : o;
            atomicAdd(out + (size_t)cur * 64 + quad * 16 + l16, o);

            // advance to next distinct dst in tile
            int nxt = 0x7fffffff;
            #pragma unroll
            for (int r = 0; r < 4; ++r)
                if (dr[r] > cur && dr[r] < nxt) nxt = dr[r];
            int tmp = __shfl_xor(nxt, 16); nxt = (tmp < nxt) ? tmp : nxt;
            tmp = __shfl_xor(nxt, 32);     nxt = (tmp < nxt) ? tmp : nxt;
            if (nxt == 0x7fffffff) break;
            cur = nxt;
        }
    }
}

// ---------------------------------------------------------------------------
// Fallback: original atomic-scatter kernel (used only if workspace too small)
// ---------------------------------------------------------------------------
__global__ __launch_bounds__(256, 2) void cfconv_kernel(
    const float* __restrict__ nw, const float* __restrict__ rbf,
    const float* __restrict__ W1, const float* __restrict__ b1,
    const float* __restrict__ W2, const float* __restrict__ b2,
    const int* __restrict__ src, const int* __restrict__ dst,
    float* __restrict__ out, int n_edges)
{
    __shared__ __align__(16) short lds_h[4][16 * 72];

    const int tid  = threadIdx.x;
    const int wave = tid >> 6;
    const int lane = tid & 63;
    const int l16  = lane & 15;
    const int quad = lane >> 4;

    bf16x8 w1f[2][4], w2f[2][4];
    #pragma unroll
    for (int ks = 0; ks < 2; ++ks) {
        #pragma unroll
        for (int nt = 0; nt < 4; ++nt) {
            const int col = l16 + 16 * nt;
            const int k0  = quad * 8 + 32 * ks;
            bf16x8 a, b;
            #pragma unroll
            for (int j = 0; j < 8; ++j) {
                a[j] = f2bf(W1[(k0 + j) * 64 + col]);
                b[j] = f2bf(W2[(k0 + j) * 64 + col]);
            }
            w1f[ks][nt] = a;
            w2f[ks][nt] = b;
        }
    }
    float b1v[4], b2v[4];
    #pragma unroll
    for (int nt = 0; nt < 4; ++nt) {
        b1v[nt] = b1[l16 + 16 * nt];
        b2v[nt] = b2[l16 + 16 * nt];
    }

    short* myh = lds_h[wave];
    const int ntiles = (n_edges + 15) >> 4;
    const int gw = blockIdx.x * 4 + wave;
    const int stride = gridDim.x * 4;

    for (int t = gw; t < ntiles; t += stride) {
        const int e0 = t * 16;
        int arow = e0 + l16;
        if (arow >= n_edges) arow = n_edges - 1;
        const float* rp = rbf + (size_t)arow * 64 + quad * 8;
        bf16x8 af[2];
        #pragma unroll
        for (int ks = 0; ks < 2; ++ks) {
            float4 lo = *(const float4*)(rp + 32 * ks);
            float4 hi = *(const float4*)(rp + 32 * ks + 4);
            bf16x8 a;
            a[0] = f2bf(lo.x); a[1] = f2bf(lo.y); a[2] = f2bf(lo.z); a[3] = f2bf(lo.w);
            a[4] = f2bf(hi.x); a[5] = f2bf(hi.y); a[6] = f2bf(hi.z); a[7] = f2bf(hi.w);
            af[ks] = a;
        }

        f32x4 acc[4] = { {0.f,0.f,0.f,0.f}, {0.f,0.f,0.f,0.f},
                         {0.f,0.f,0.f,0.f}, {0.f,0.f,0.f,0.f} };
        #pragma unroll
        for (int nt = 0; nt < 4; ++nt)
            #pragma unroll
            for (int ks = 0; ks < 2; ++ks)
                acc[nt] = __builtin_amdgcn_mfma_f32_16x16x32_bf16(
                    af[ks], w1f[ks][nt], acc[nt], 0, 0, 0);

        #pragma unroll
        for (int nt = 0; nt < 4; ++nt)
            #pragma unroll
            for (int r = 0; r < 4; ++r)
                myh[(quad * 4 + r) * 72 + l16 + 16 * nt] =
                    f2bf(ssp(acc[nt][r] + b1v[nt]));

        bf16x8 hf[2];
        #pragma unroll
        for (int ks = 0; ks < 2; ++ks)
            hf[ks] = *(const bf16x8*)(myh + l16 * 72 + quad * 8 + 32 * ks);

        f32x4 acc2[4] = { {0.f,0.f,0.f,0.f}, {0.f,0.f,0.f,0.f},
                          {0.f,0.f,0.f,0.f}, {0.f,0.f,0.f,0.f} };
        #pragma unroll
        for (int nt = 0; nt < 4; ++nt)
            #pragma unroll
            for (int ks = 0; ks < 2; ++ks)
                acc2[nt] = __builtin_amdgcn_mfma_f32_16x16x32_bf16(
                    hf[ks], w2f[ks][nt], acc2[nt], 0, 0, 0);

        #pragma unroll
        for (int r = 0; r < 4; ++r) {
            const int e = e0 + quad * 4 + r;
            if (e < n_edges) {
                const int s = src[e], d = dst[e];
                const float* nwp = nw + (size_t)s * 64;
                float* op = out + (size_t)d * 64;
                #pragma unroll
                for (int nt = 0; nt < 4; ++nt) {
                    const int col = l16 + 16 * nt;
                    atomicAdd(op + col, (acc2[nt][r] + b2v[nt]) * nwp[col]);
                }
            }
        }
    }
}

extern "C" void kernel_launch(void* const* d_in, const int* in_sizes, int n_in,
                              void* d_out, int out_size, void* d_ws, size_t ws_size,
                              hipStream_t stream) {
    const float* nw  = (const float*)d_in[0];
    const float* rbf = (const float*)d_in[1];
    const float* W1  = (const float*)d_in[2];
    const float* b1  = (const float*)d_in[3];
    const float* W2  = (const float*)d_in[4];
    const float* b2  = (const float*)d_in[5];
    const int*   src = (const int*)d_in[6];
    const int*   dst = (const int*)d_in[7];
    float* out = (float*)d_out;
    const int n_edges = in_sizes[6];
    const int n_nodes = out_size / 64;

    // workspace: base[n+1] | counts[n] | partials[1024] | perm[E] | sp[E] | dp[E]
    const size_t need = ((size_t)(n_nodes + 1) + (size_t)n_nodes + 1024
                         + 3 * (size_t)n_edges) * sizeof(int);

    if (ws_size >= need) {
        int* base     = (int*)d_ws;
        int* counts   = base + (n_nodes + 1);
        int* partials = counts + n_nodes;
        int* perm     = partials + 1024;
        int* sp       = perm + n_edges;
        int* dp       = sp + n_edges;

        const int nblk = (n_nodes + 1023) / 1024;
        int eblocks = (n_edges + 255) / 256;
        if (eblocks > 8192) eblocks = 8192;

        hipMemsetAsync(counts, 0, (size_t)n_nodes * sizeof(int), stream);
        hipLaunchKernelGGL(hist_kernel, dim3(eblocks), dim3(256), 0, stream,
                           dst, counts, n_edges);
        hipLaunchKernelGGL(scan_blocks, dim3(nblk), dim3(256), 0, stream,
                           counts, base, partials, n_nodes);
        hipLaunchKernelGGL(scan_partials, dim3(1), dim3(64), 0, stream,
                           partials, nblk);
        hipLaunchKernelGGL(add_offsets, dim3(nblk), dim3(256), 0, stream,
                           base, partials, n_nodes, n_edges);
        hipMemsetAsync(counts, 0, (size_t)n_nodes * sizeof(int), stream);
        hipLaunchKernelGGL(scatter_kernel, dim3(eblocks), dim3(256), 0, stream,
                           dst, src, base, counts, perm, sp, dp, n_edges);

        hipMemsetAsync(out, 0, (size_t)out_size * sizeof(float), stream);
        hipLaunchKernelGGL(cfconv_perm, dim3(1024), dim3(256), 0, stream,
                           nw, rbf, W1, b1, W2, b2, perm, sp, dp, out, n_edges);
    } else {
        // fallback: original atomic path
        hipMemsetAsync(out, 0, (size_t)out_size * sizeof(float), stream);
        hipLaunchKernelGGL(cfconv_kernel, dim3(1024), dim3(256), 0, stream,
                           nw, rbf, W1, b1, W2, b2, src, dst, out, n_edges);
    }
}